// Round 14
// baseline (218.451 us; speedup 1.0000x reference)
//
#include <hip/hip_runtime.h>
#include <cmath>

// Problem constants (B=4, S=4096, D=4096, E=64, K=8)
#define NTOK 16384
#define DDIM 4096
#define NEXP 64
#define TOPK 8
#define TPB    32               // tokens per block
#define KSPLIT 4                // K-split ways
#define KSL    1024             // K per wave slice
#define NSTEP  32               // k32 steps per wave
#define EPS_GAP 2.5e-4f         // ambiguity margin; bf16 trunc-split sigma ~1.5e-5

typedef __attribute__((ext_vector_type(8))) short short8;   // 8 bf16
typedef __attribute__((ext_vector_type(4))) float f32x4;

// trunc split: hi = top 16 bits (residual exact), lo = trunc16(f - hi).
#define CVT1(f, hOut, lOut, j) do {                                          \
    unsigned _u = __builtin_bit_cast(unsigned, (float)(f));                  \
    float _hf = __builtin_bit_cast(float, _u & 0xFFFF0000u);                 \
    hOut[j] = (short)(_u >> 16);                                             \
    lOut[j] = (short)(__builtin_bit_cast(unsigned, (float)((f) - _hf)) >> 16);\
} while (0)
#define CONV8(vA, vB, hOut, lOut) do {                       \
    CVT1(vA.x, hOut, lOut, 0); CVT1(vA.y, hOut, lOut, 1);    \
    CVT1(vA.z, hOut, lOut, 2); CVT1(vA.w, hOut, lOut, 3);    \
    CVT1(vB.x, hOut, lOut, 4); CVT1(vB.y, hOut, lOut, 5);    \
    CVT1(vB.z, hOut, lOut, 6); CVT1(vB.w, hOut, lOut, 7);    \
} while (0)

// ---------------------------------------------------------------------------
// Kernel 0 (R10-verified): W -> lane-ordered bf16 hi/lo blob.
// blob[c32 0..127][n 0..3][granule=lane][16B], lo at +1024 within n-block.
// Consumer lane l reads expert e = n*16+(l&15), k = c*32+(l>>4)*8+j.
// ---------------------------------------------------------------------------
__global__ __launch_bounds__(256) void prep_w(const float* __restrict__ W,
                                              unsigned char* __restrict__ blob,
                                              int* __restrict__ flag_cnt)
{
    __shared__ float tile[32][65];
    const int c = blockIdx.x;                 // k-window [c*32, c*32+32)
    const int t = threadIdx.x;
    if (c == 0 && t == 0) *flag_cnt = 0;
    {
        const int r = t >> 3, q = t & 7;      // row, 8-float slice
        float4 v0 = *reinterpret_cast<const float4*>(
            &W[(size_t)(c * 32 + r) * NEXP + q * 8]);
        float4 v1 = *reinterpret_cast<const float4*>(
            &W[(size_t)(c * 32 + r) * NEXP + q * 8 + 4]);
        tile[r][q * 8 + 0] = v0.x; tile[r][q * 8 + 1] = v0.y;
        tile[r][q * 8 + 2] = v0.z; tile[r][q * 8 + 3] = v0.w;
        tile[r][q * 8 + 4] = v1.x; tile[r][q * 8 + 5] = v1.y;
        tile[r][q * 8 + 6] = v1.z; tile[r][q * 8 + 7] = v1.w;
    }
    __syncthreads();
    {
        const int el   = t & 15;
        const int kgrp = (t >> 4) & 3;
        const int n    = t >> 6;
        short8 hv, lv;
#pragma unroll
        for (int j = 0; j < 8; ++j) {
            float f = tile[kgrp * 8 + j][n * 16 + el];
            CVT1(f, hv, lv, j);
        }
        unsigned char* base = blob + (size_t)c * 8192 + n * 2048 +
                              (kgrp * 16 + el) * 16;
        *reinterpret_cast<short8*>(base)        = hv;   // hi
        *reinterpret_cast<short8*>(base + 1024) = lv;   // lo
    }
}

// ---------------------------------------------------------------------------
// Kernel 1: barrier-free direct-to-register MFMA GEMM.
// 512 blocks x 512 thr (8 waves = 2 tokgrp x 4 ksplit). Wave = 16 tok x
// 64 exp over 1024 K (32 steps of k32). Per step: 2 A float4 (fragment-
// direct, coalesced 128B/row) + 8 B short8 (lane-ordered blob, L1/L2-hot)
// + CONV8 + 12 MFMA. 2-step-deep NAMED-register pipeline (A/B alternating
// sets), no LDS / no barriers in the loop. K-split reduced in LDS at end.
// ---------------------------------------------------------------------------
__global__ __launch_bounds__(512, 4) void bulk_kernel(
    const float* __restrict__ x, const unsigned char* __restrict__ blob,
    const float* __restrict__ b,
    float* __restrict__ g_out, float* __restrict__ i_out,
    float* __restrict__ s_out,
    int* __restrict__ flag_cnt, int* __restrict__ flag_list, int flag_cap)
{
    __shared__ float red[KSPLIT][TPB][NEXP + 4];   // 34.8 KB
    __shared__ float lsv[TPB][NEXP + 1];           // 8.3 KB

    const int tid  = threadIdx.x;
    const int l    = tid & 63;
    const int w    = tid >> 6;
    const int tg   = w & 1;                  // token group (16 tokens)
    const int ks   = w >> 1;                 // K-split slice
    const int tok0 = blockIdx.x * TPB;

    const int mt   = l & 15;
    const int kgrp = l >> 4;

    const float* aPtr = x + (size_t)(tok0 + tg * 16 + mt) * DDIM +
                        ks * KSL + kgrp * 8;
    const unsigned char* bPtr = blob + (size_t)(ks * NSTEP) * 8192 + l * 16;

    f32x4 acc0 = (f32x4){0.f,0.f,0.f,0.f};
    f32x4 acc1 = (f32x4){0.f,0.f,0.f,0.f};
    f32x4 acc2 = (f32x4){0.f,0.f,0.f,0.f};
    f32x4 acc3 = (f32x4){0.f,0.f,0.f,0.f};

#define LOADA(g0, g1, s) do {                                                 \
    const float* _p = aPtr + (size_t)(s) * 32;                                \
    g0 = *reinterpret_cast<const float4*>(_p);                                \
    g1 = *reinterpret_cast<const float4*>(_p + 4);                            \
} while (0)

#define LOADB(H0,H1,H2,H3,L0,L1,L2,L3, s) do {                                \
    const unsigned char* _p = bPtr + (size_t)(s) * 8192;                      \
    H0 = *reinterpret_cast<const short8*>(_p);                                \
    L0 = *reinterpret_cast<const short8*>(_p + 1024);                         \
    H1 = *reinterpret_cast<const short8*>(_p + 2048);                         \
    L1 = *reinterpret_cast<const short8*>(_p + 3072);                         \
    H2 = *reinterpret_cast<const short8*>(_p + 4096);                         \
    L2 = *reinterpret_cast<const short8*>(_p + 5120);                         \
    H3 = *reinterpret_cast<const short8*>(_p + 6144);                         \
    L3 = *reinterpret_cast<const short8*>(_p + 7168);                         \
} while (0)

#define DOMFMA(H0,H1,H2,H3,L0,L1,L2,L3) do {                                  \
    acc0 = __builtin_amdgcn_mfma_f32_16x16x32_bf16(ah, H0, acc0, 0, 0, 0);    \
    acc0 = __builtin_amdgcn_mfma_f32_16x16x32_bf16(ah, L0, acc0, 0, 0, 0);    \
    acc0 = __builtin_amdgcn_mfma_f32_16x16x32_bf16(al, H0, acc0, 0, 0, 0);    \
    acc1 = __builtin_amdgcn_mfma_f32_16x16x32_bf16(ah, H1, acc1, 0, 0, 0);    \
    acc1 = __builtin_amdgcn_mfma_f32_16x16x32_bf16(ah, L1, acc1, 0, 0, 0);    \
    acc1 = __builtin_amdgcn_mfma_f32_16x16x32_bf16(al, H1, acc1, 0, 0, 0);    \
    acc2 = __builtin_amdgcn_mfma_f32_16x16x32_bf16(ah, H2, acc2, 0, 0, 0);    \
    acc2 = __builtin_amdgcn_mfma_f32_16x16x32_bf16(ah, L2, acc2, 0, 0, 0);    \
    acc2 = __builtin_amdgcn_mfma_f32_16x16x32_bf16(al, H2, acc2, 0, 0, 0);    \
    acc3 = __builtin_amdgcn_mfma_f32_16x16x32_bf16(ah, H3, acc3, 0, 0, 0);    \
    acc3 = __builtin_amdgcn_mfma_f32_16x16x32_bf16(ah, L3, acc3, 0, 0, 0);    \
    acc3 = __builtin_amdgcn_mfma_f32_16x16x32_bf16(al, H3, acc3, 0, 0, 0);    \
} while (0)

    // ---- 2-deep pipeline, alternating named sets A/B ----
    float4 a0A, a1A, a0B, a1B;
    short8 h0A,h1A,h2A,h3A,l0A,l1A,l2A,l3A;
    short8 h0B,h1B,h2B,h3B,l0B,l1B,l2B,l3B;

    LOADA(a0A, a1A, 0); LOADB(h0A,h1A,h2A,h3A,l0A,l1A,l2A,l3A, 0);
    LOADA(a0B, a1B, 1); LOADB(h0B,h1B,h2B,h3B,l0B,l1B,l2B,l3B, 1);

    for (int s2 = 0; s2 < NSTEP / 2 - 1; ++s2) {
        const int s = 2 * s2;
        {
            short8 ah, al;
            CONV8(a0A, a1A, ah, al);
            DOMFMA(h0A,h1A,h2A,h3A,l0A,l1A,l2A,l3A);
        }
        LOADA(a0A, a1A, s + 2); LOADB(h0A,h1A,h2A,h3A,l0A,l1A,l2A,l3A, s + 2);
        {
            short8 ah, al;
            CONV8(a0B, a1B, ah, al);
            DOMFMA(h0B,h1B,h2B,h3B,l0B,l1B,l2B,l3B);
        }
        LOADA(a0B, a1B, s + 3); LOADB(h0B,h1B,h2B,h3B,l0B,l1B,l2B,l3B, s + 3);
    }
    {   // tail: steps 30, 31 already loaded
        short8 ah, al;
        CONV8(a0A, a1A, ah, al);
        DOMFMA(h0A,h1A,h2A,h3A,l0A,l1A,l2A,l3A);
    }
    {
        short8 ah, al;
        CONV8(a0B, a1B, ah, al);
        DOMFMA(h0B,h1B,h2B,h3B,l0B,l1B,l2B,l3B);
    }
#undef LOADA
#undef LOADB
#undef DOMFMA

    // ---- K-split partials -> LDS (verified C mapping: col=mt, row=kgrp*4+r)
#pragma unroll
    for (int r = 0; r < 4; ++r) {
        const int trow = tg * 16 + kgrp * 4 + r;
        red[ks][trow][ 0 + mt] = acc0[r];
        red[ks][trow][16 + mt] = acc1[r];
        red[ks][trow][32 + mt] = acc2[r];
        red[ks][trow][48 + mt] = acc3[r];
    }
    __syncthreads();

    // ---- fixed-order reduce + bias + sigmoid + s_out + logits ----
    {
        const int t  = tid >> 4;             // token 0..31
        const int e0 = (tid & 15) * 4;       // expert base
        float4 v0 = *reinterpret_cast<const float4*>(&red[0][t][e0]);
        float4 v1 = *reinterpret_cast<const float4*>(&red[1][t][e0]);
        float4 v2 = *reinterpret_cast<const float4*>(&red[2][t][e0]);
        float4 v3 = *reinterpret_cast<const float4*>(&red[3][t][e0]);
        float4 bv = *reinterpret_cast<const float4*>(&b[e0]);
        float s0 = ((v0.x + v1.x) + (v2.x + v3.x)) + bv.x;
        float s1 = ((v0.y + v1.y) + (v2.y + v3.y)) + bv.y;
        float s2 = ((v0.z + v1.z) + (v2.z + v3.z)) + bv.z;
        float s3 = ((v0.w + v1.w) + (v2.w + v3.w)) + bv.w;
        lsv[t][e0 + 0] = s0; lsv[t][e0 + 1] = s1;
        lsv[t][e0 + 2] = s2; lsv[t][e0 + 3] = s3;
        float4 sv;
        sv.x = 1.0f / (1.0f + __expf(-s0));
        sv.y = 1.0f / (1.0f + __expf(-s1));
        sv.z = 1.0f / (1.0f + __expf(-s2));
        sv.w = 1.0f / (1.0f + __expf(-s3));
        *reinterpret_cast<float4*>(&s_out[(size_t)(tok0 + t) * NEXP + e0]) = sv;
    }
    __syncthreads();

    // ---- top-10 scan, one lane per token ----
    if (tid < TPB) {
        const int t = tid;
        float val[10];
        int   idx[10];
#pragma unroll
        for (int j = 0; j < 10; ++j) { val[j] = -1e30f; idx[j] = 0; }

        for (int e = 0; e < NEXP; ++e) {
            float v = lsv[t][e];
            int  ei = e;
#pragma unroll
            for (int j = 0; j < 10; ++j) {
                if (v > val[j]) {    // strict > keeps lower index first on ties
                    float tv = val[j]; val[j] = v; v = tv;
                    int   ti = idx[j]; idx[j] = ei; ei = ti;
                }
            }
        }

        bool flag = false;
#pragma unroll
        for (int j = 0; j < 9; ++j) flag |= (val[j] - val[j + 1]) < EPS_GAP;

        float gg[TOPK], gsum = 0.0f;
#pragma unroll
        for (int j = 0; j < TOPK; ++j) {
            gg[j] = 1.0f / (1.0f + __expf(-val[j]));
            gsum += gg[j];
        }
        const float inv = 1.0f / gsum;
        const int tglob = tok0 + t;
#pragma unroll
        for (int j = 0; j < TOPK; ++j) {
            g_out[(size_t)tglob * TOPK + j] = gg[j] * inv;
            i_out[(size_t)tglob * TOPK + j] = (float)idx[j];
        }
        if (flag) {
            int p = atomicAdd(flag_cnt, 1);
            if (p < flag_cap) flag_list[p] = tglob;
        }
    }
}

// ---------------------------------------------------------------------------
// Kernel 2: f64-exact re-rank of ambiguous tokens (verified).
// ---------------------------------------------------------------------------
__global__ __launch_bounds__(256) void refine64(
    const float* __restrict__ x, const float* __restrict__ W,
    const float* __restrict__ b, float* __restrict__ g_out,
    float* __restrict__ i_out, float* __restrict__ s_out,
    const int* __restrict__ flag_cnt, const int* __restrict__ flag_list,
    int flag_cap)
{
    __shared__ float  xs2[DDIM];
    __shared__ double red[4][NEXP];
    __shared__ double sc[NEXP];

    const int tid = threadIdx.x;
    int count = *flag_cnt;
    if (count > flag_cap) count = flag_cap;

    for (int it = blockIdx.x; it < count; it += gridDim.x) {
        const int tok = flag_list[it];
        __syncthreads();
#pragma unroll
        for (int q = 0; q < 4; ++q) {
            int fi = tid + 256 * q;
            *reinterpret_cast<float4*>(&xs2[fi * 4]) =
                *reinterpret_cast<const float4*>(&x[(size_t)tok * DDIM + fi * 4]);
        }
        __syncthreads();

        const int e    = tid & 63;
        const int part = tid >> 6;
        const int dbase = part * (DDIM / 4);
        double a = 0.0;
        for (int d = 0; d < DDIM / 4; ++d) {
            a = fma((double)xs2[dbase + d],
                    (double)W[(size_t)(dbase + d) * NEXP + e], a);
        }
        red[part][e] = a;
        __syncthreads();

        if (tid < NEXP) {
            double z = ((red[0][tid] + red[1][tid]) +
                        (red[2][tid] + red[3][tid])) + (double)b[tid];
            double s = 1.0 / (1.0 + exp(-z));
            sc[tid] = s;
            s_out[(size_t)tok * NEXP + tid] = (float)s;
        }
        __syncthreads();

        if (tid == 0) {
            double val[TOPK];
            int    idx[TOPK];
#pragma unroll
            for (int j = 0; j < TOPK; ++j) { val[j] = -1e30; idx[j] = 0; }
            for (int e2 = 0; e2 < NEXP; ++e2) {
                double v = sc[e2];
                int   ei = e2;
#pragma unroll
                for (int j = 0; j < TOPK; ++j) {
                    if (v > val[j]) {
                        double tv = val[j]; val[j] = v; v = tv;
                        int    ti = idx[j]; idx[j] = ei; ei = ti;
                    }
                }
            }
            double gsum = 0.0;
#pragma unroll
            for (int j = 0; j < TOPK; ++j) gsum += val[j];
            const double inv = 1.0 / gsum;
#pragma unroll
            for (int j = 0; j < TOPK; ++j) {
                g_out[(size_t)tok * TOPK + j] = (float)(val[j] * inv);
                i_out[(size_t)tok * TOPK + j] = (float)idx[j];
            }
        }
        __syncthreads();
    }
}

// ---------------------------------------------------------------------------
extern "C" void kernel_launch(void* const* d_in, const int* in_sizes, int n_in,
                              void* d_out, int out_size, void* d_ws, size_t ws_size,
                              hipStream_t stream)
{
    (void)in_sizes; (void)n_in; (void)out_size;
    const float* x = (const float*)d_in[0];
    const float* W = (const float*)d_in[1];
    const float* b = (const float*)d_in[2];

    float* g_out = (float*)d_out;                       // [NTOK, 8]
    float* i_out = g_out + (size_t)NTOK * TOPK;         // [NTOK, 8] indices as float
    float* s_out = i_out + (size_t)NTOK * TOPK;         // [NTOK, 64]

    const size_t OFF_LIST = 1024;
    const size_t OFF_BLOB = 131072;
    const size_t WS_NEED  = OFF_BLOB + 128u * 8192u;    // +1 MB blob
    if (ws_size < WS_NEED) return;

    char* ws = (char*)d_ws;
    int* cnt  = (int*)ws;
    int* list = (int*)(ws + OFF_LIST);
    unsigned char* blob = (unsigned char*)(ws + OFF_BLOB);
    int cap = NTOK;

    prep_w<<<128, 256, 0, stream>>>(W, blob, cnt);
    bulk_kernel<<<NTOK / TPB, 512, 0, stream>>>(x, blob, b,
                                                g_out, i_out, s_out,
                                                cnt, list, cap);
    refine64<<<256, 256, 0, stream>>>(x, W, b, g_out, i_out, s_out,
                                      cnt, list, cap);
}

// Round 15
// 210.838 us; speedup vs baseline: 1.0361x; 1.0361x over previous
//
#include <hip/hip_runtime.h>
#include <cmath>

// Problem constants (B=4, S=4096, D=4096, E=64, K=8)
#define NTOK 16384
#define DDIM 4096
#define NEXP 64
#define TOPK 8
#define TPB  32                 // tokens per block
#define BK   64                 // K per staged step
#define NSTEP (DDIM / BK)       // 64
#define EPS_GAP 2.5e-4f         // ambiguity margin; trunc-split GEMM err sigma ~2e-5

typedef __attribute__((ext_vector_type(8))) short short8;   // 8 bf16
typedef __attribute__((ext_vector_type(4))) float f32x4;

__device__ __forceinline__ void gload16(const void* g, void* l) {
    __builtin_amdgcn_global_load_lds(
        (const __attribute__((address_space(1))) unsigned int*)g,
        (__attribute__((address_space(3))) unsigned int*)l, 16, 0, 0);
}

// trunc split: hi = top 16 bits (residual exact), lo = trunc16(f - hi).
#define CVT1(f, hOut, lOut, j) do {                                          \
    unsigned _u = __builtin_bit_cast(unsigned, (float)(f));                  \
    float _hf = __builtin_bit_cast(float, _u & 0xFFFF0000u);                 \
    hOut[j] = (short)(_u >> 16);                                             \
    lOut[j] = (short)(__builtin_bit_cast(unsigned, (float)((f) - _hf)) >> 16);\
} while (0)

// ---------------------------------------------------------------------------
// Kernel 0 (R7-verified): W -> per-64k-chunk swizzled B images.
// chunk c: expert e row = 256B [hi 128B | lo 128B], 16B granules XOR ((e&15)<<4).
// ---------------------------------------------------------------------------
__global__ __launch_bounds__(256) void prep_w(const float* __restrict__ W,
                                              unsigned char* __restrict__ blob,
                                              int* __restrict__ flag_cnt)
{
    __shared__ float tile[64][65];
    const int c = blockIdx.x;
    const int t = threadIdx.x;
    if (c == 0 && t == 0) *flag_cnt = 0;
    {
        const int r = t >> 2, q = t & 3;
#pragma unroll
        for (int p = 0; p < 4; ++p) {
            float4 v = *reinterpret_cast<const float4*>(
                &W[(size_t)(c * BK + r) * NEXP + q * 16 + p * 4]);
            tile[r][q * 16 + p * 4 + 0] = v.x;
            tile[r][q * 16 + p * 4 + 1] = v.y;
            tile[r][q * 16 + p * 4 + 2] = v.z;
            tile[r][q * 16 + p * 4 + 3] = v.w;
        }
    }
    __syncthreads();
    {
        const int e = t >> 2, q = t & 3;
        const int swz = (e & 15) << 4;
#pragma unroll
        for (int g = 0; g < 2; ++g) {
            const int k0 = q * 16 + g * 8;
            short8 hv, lv;
#pragma unroll
            for (int j = 0; j < 8; ++j) {
                float f = tile[k0 + j][e];
                CVT1(f, hv, lv, j);
            }
            unsigned char* base = blob + (size_t)c * 16384 + e * 256;
            *reinterpret_cast<short8*>(base + ((k0 * 2) ^ swz))       = hv;
            *reinterpret_cast<short8*>(base + ((128 + k0 * 2) ^ swz)) = lv;
        }
    }
}

// ---------------------------------------------------------------------------
// Kernel 1: R7's verified LDS-staged MFMA GEMM + PER-BLOCK K-PHASE ROTATION.
// 512 blocks x 512 thr (8 waves = 4 expgrp x 2 khalf). Block = 32tok x 64exp.
// THE ONE CHANGE vs R7: physical chunk index cc = (c + 37*blockIdx.x) & 63 —
// decorrelates the chip-wide read window across L3 slices / HBM channels
// (all blocks otherwise walk the SAME 256B window of every 16KB row page in
// lockstep; suspected slice-serialization => the ~1.7 TB/s plateau).
// ---------------------------------------------------------------------------
__global__ __launch_bounds__(512, 2) void bulk_kernel(
    const float* __restrict__ x, const unsigned char* __restrict__ blob,
    const float* __restrict__ b,
    float* __restrict__ g_out, float* __restrict__ i_out,
    float* __restrict__ s_out,
    int* __restrict__ flag_cnt, int* __restrict__ flag_list, int flag_cap)
{
    __shared__ __align__(16) unsigned char smem[49152];  // A[2][8K] | B[2][16K]

    const int tid  = threadIdx.x;
    const int l    = tid & 63;
    const int w    = tid >> 6;
    const int tok0 = blockIdx.x * TPB;
    const int off  = ((int)blockIdx.x * 37) & (NSTEP - 1);   // K-phase rotation

    // ---- staging sources (A pre-swizzled per-lane; B linear from blob) ----
    const int sTok   = tid >> 4;                 // 0..31
    const int sInner = (tid * 16) & 255;
    const float* aSrc = x + (size_t)(tok0 + sTok) * DDIM +
        ((((unsigned)sInner) ^ ((sTok & 15) << 4)) >> 2);
    const unsigned char* bSrc = blob + tid * 16;

#define STAGE(buf, cc) do {                                                   \
    gload16(aSrc + (size_t)(cc) * BK, smem + (buf) * 8192 + tid * 16);        \
    gload16(bSrc + (size_t)(cc) * 16384,                                      \
            smem + 16384 + (buf) * 16384 + tid * 16);                         \
    gload16(bSrc + (size_t)(cc) * 16384 + 8192,                               \
            smem + 16384 + (buf) * 16384 + 8192 + tid * 16);                  \
} while (0)

    // ---- compute-lane constants ----
    const int expgrp = w & 3;
    const int khalf  = w >> 2;
    const int mt     = l & 15;
    const int kgrp   = l >> 4;
    const int kk     = khalf * 32 + kgrp * 8;
    const int myE    = expgrp * 16 + mt;
    const int aswz   = mt << 4;
    const int aoff0  = mt * 256 + ((kk * 4) ^ aswz);
    const int eswz   = (myE & 15) << 4;
    const int boffh  = myE * 256 + ((kk * 2) ^ eswz);
    const int boffl  = myE * 256 + (((128 + kk * 2)) ^ eswz);

    f32x4 acc0 = (f32x4){0.f, 0.f, 0.f, 0.f};
    f32x4 acc1 = (f32x4){0.f, 0.f, 0.f, 0.f};

#define COMPUTE(buf) do {                                                     \
    const unsigned char* _a = smem + (buf) * 8192;                            \
    const unsigned char* _b = smem + 16384 + (buf) * 16384;                   \
    float4 A00 = *reinterpret_cast<const float4*>(_a + aoff0);                \
    float4 A01 = *reinterpret_cast<const float4*>(_a + (aoff0 ^ 16));         \
    float4 A10 = *reinterpret_cast<const float4*>(_a + 4096 + aoff0);         \
    float4 A11 = *reinterpret_cast<const float4*>(_a + 4096 + (aoff0 ^ 16));  \
    short8 ah0, al0, ah1, al1;                                                \
    CVT1(A00.x, ah0, al0, 0); CVT1(A00.y, ah0, al0, 1);                       \
    CVT1(A00.z, ah0, al0, 2); CVT1(A00.w, ah0, al0, 3);                       \
    CVT1(A01.x, ah0, al0, 4); CVT1(A01.y, ah0, al0, 5);                       \
    CVT1(A01.z, ah0, al0, 6); CVT1(A01.w, ah0, al0, 7);                       \
    CVT1(A10.x, ah1, al1, 0); CVT1(A10.y, ah1, al1, 1);                       \
    CVT1(A10.z, ah1, al1, 2); CVT1(A10.w, ah1, al1, 3);                       \
    CVT1(A11.x, ah1, al1, 4); CVT1(A11.y, ah1, al1, 5);                       \
    CVT1(A11.z, ah1, al1, 6); CVT1(A11.w, ah1, al1, 7);                       \
    short8 bh = *reinterpret_cast<const short8*>(_b + boffh);                 \
    short8 bl = *reinterpret_cast<const short8*>(_b + boffl);                 \
    acc0 = __builtin_amdgcn_mfma_f32_16x16x32_bf16(ah0, bh, acc0, 0, 0, 0);   \
    acc0 = __builtin_amdgcn_mfma_f32_16x16x32_bf16(ah0, bl, acc0, 0, 0, 0);   \
    acc0 = __builtin_amdgcn_mfma_f32_16x16x32_bf16(al0, bh, acc0, 0, 0, 0);   \
    acc1 = __builtin_amdgcn_mfma_f32_16x16x32_bf16(ah1, bh, acc1, 0, 0, 0);   \
    acc1 = __builtin_amdgcn_mfma_f32_16x16x32_bf16(ah1, bl, acc1, 0, 0, 0);   \
    acc1 = __builtin_amdgcn_mfma_f32_16x16x32_bf16(al1, bh, acc1, 0, 0, 0);   \
} while (0)

    STAGE(0, off);
    __syncthreads();
    for (int c = 0; c < NSTEP; ++c) {
        if (c + 1 < NSTEP) {
            const int cc = (c + 1 + off) & (NSTEP - 1);
            STAGE((c + 1) & 1, cc);
        }
        COMPUTE(c & 1);
        __syncthreads();
    }

    // ---- K-split reduce through LDS (reuse staging buffers) ----
    float* red = (float*)smem;                   // [2][32][68]
    float* ls  = (float*)(smem + 17408);         // [32][65]
    {
        float* rh = red + khalf * (32 * 68);
#pragma unroll
        for (int r = 0; r < 4; ++r) {
            rh[(kgrp * 4 + r) * 68 + myE]        = acc0[r];
            rh[(16 + kgrp * 4 + r) * 68 + myE]   = acc1[r];
        }
    }
    __syncthreads();

    // ---- fixed-order sum + bias + sigmoid + s_out + logits ----
    {
        const int t  = tid >> 4;                 // token 0..31
        const int e0 = (tid & 15) * 4;
        float4 v0 = *reinterpret_cast<const float4*>(red + t * 68 + e0);
        float4 v1 = *reinterpret_cast<const float4*>(red + 2176 + t * 68 + e0);
        float4 bv = *reinterpret_cast<const float4*>(&b[e0]);
        float s0 = v0.x + v1.x + bv.x;
        float s1 = v0.y + v1.y + bv.y;
        float s2 = v0.z + v1.z + bv.z;
        float s3 = v0.w + v1.w + bv.w;
        ls[t * 65 + e0 + 0] = s0; ls[t * 65 + e0 + 1] = s1;
        ls[t * 65 + e0 + 2] = s2; ls[t * 65 + e0 + 3] = s3;
        float4 sv;
        sv.x = 1.0f / (1.0f + __expf(-s0));
        sv.y = 1.0f / (1.0f + __expf(-s1));
        sv.z = 1.0f / (1.0f + __expf(-s2));
        sv.w = 1.0f / (1.0f + __expf(-s3));
        *reinterpret_cast<float4*>(&s_out[(size_t)(tok0 + t) * NEXP + e0]) = sv;
    }
    __syncthreads();

    // ---- top-10 scan, one lane per token ----
    if (tid < TPB) {
        const int t = tid;
        float val[10];
        int   idx[10];
#pragma unroll
        for (int j = 0; j < 10; ++j) { val[j] = -1e30f; idx[j] = 0; }

        for (int e = 0; e < NEXP; ++e) {
            float v = ls[t * 65 + e];
            int  ei = e;
#pragma unroll
            for (int j = 0; j < 10; ++j) {
                if (v > val[j]) {    // strict > keeps lower index first on ties
                    float tv = val[j]; val[j] = v; v = tv;
                    int   ti = idx[j]; idx[j] = ei; ei = ti;
                }
            }
        }

        bool flag = false;
#pragma unroll
        for (int j = 0; j < 9; ++j) flag |= (val[j] - val[j + 1]) < EPS_GAP;

        float g[TOPK], gsum = 0.0f;
#pragma unroll
        for (int j = 0; j < TOPK; ++j) {
            g[j] = 1.0f / (1.0f + __expf(-val[j]));
            gsum += g[j];
        }
        const float inv = 1.0f / gsum;
        const int tg = tok0 + t;
#pragma unroll
        for (int j = 0; j < TOPK; ++j) {
            g_out[(size_t)tg * TOPK + j] = g[j] * inv;
            i_out[(size_t)tg * TOPK + j] = (float)idx[j];
        }
        if (flag) {
            int p = atomicAdd(flag_cnt, 1);
            if (p < flag_cap) flag_list[p] = tg;
        }
    }
#undef STAGE
#undef COMPUTE
}

// ---------------------------------------------------------------------------
// Kernel 2: f64-exact re-rank of ambiguous tokens (verified).
// ---------------------------------------------------------------------------
__global__ __launch_bounds__(256) void refine64(
    const float* __restrict__ x, const float* __restrict__ W,
    const float* __restrict__ b, float* __restrict__ g_out,
    float* __restrict__ i_out, float* __restrict__ s_out,
    const int* __restrict__ flag_cnt, const int* __restrict__ flag_list,
    int flag_cap)
{
    __shared__ float  xs2[DDIM];
    __shared__ double red[4][NEXP];
    __shared__ double sc[NEXP];

    const int tid = threadIdx.x;
    int count = *flag_cnt;
    if (count > flag_cap) count = flag_cap;

    for (int it = blockIdx.x; it < count; it += gridDim.x) {
        const int tok = flag_list[it];
        __syncthreads();
#pragma unroll
        for (int q = 0; q < 4; ++q) {
            int fi = tid + 256 * q;
            *reinterpret_cast<float4*>(&xs2[fi * 4]) =
                *reinterpret_cast<const float4*>(&x[(size_t)tok * DDIM + fi * 4]);
        }
        __syncthreads();

        const int e    = tid & 63;
        const int part = tid >> 6;
        const int dbase = part * (DDIM / 4);
        double a = 0.0;
        for (int d = 0; d < DDIM / 4; ++d) {
            a = fma((double)xs2[dbase + d],
                    (double)W[(size_t)(dbase + d) * NEXP + e], a);
        }
        red[part][e] = a;
        __syncthreads();

        if (tid < NEXP) {
            double z = ((red[0][tid] + red[1][tid]) +
                        (red[2][tid] + red[3][tid])) + (double)b[tid];
            double s = 1.0 / (1.0 + exp(-z));
            sc[tid] = s;
            s_out[(size_t)tok * NEXP + tid] = (float)s;
        }
        __syncthreads();

        if (tid == 0) {
            double val[TOPK];
            int    idx[TOPK];
#pragma unroll
            for (int j = 0; j < TOPK; ++j) { val[j] = -1e30; idx[j] = 0; }
            for (int e2 = 0; e2 < NEXP; ++e2) {
                double v = sc[e2];
                int   ei = e2;
#pragma unroll
                for (int j = 0; j < TOPK; ++j) {
                    if (v > val[j]) {
                        double tv = val[j]; val[j] = v; v = tv;
                        int    ti = idx[j]; idx[j] = ei; ei = ti;
                    }
                }
            }
            double gsum = 0.0;
#pragma unroll
            for (int j = 0; j < TOPK; ++j) gsum += val[j];
            const double inv = 1.0 / gsum;
#pragma unroll
            for (int j = 0; j < TOPK; ++j) {
                g_out[(size_t)tok * TOPK + j] = (float)(val[j] * inv);
                i_out[(size_t)tok * TOPK + j] = (float)idx[j];
            }
        }
        __syncthreads();
    }
}

// ---------------------------------------------------------------------------
extern "C" void kernel_launch(void* const* d_in, const int* in_sizes, int n_in,
                              void* d_out, int out_size, void* d_ws, size_t ws_size,
                              hipStream_t stream)
{
    (void)in_sizes; (void)n_in; (void)out_size;
    const float* x = (const float*)d_in[0];
    const float* W = (const float*)d_in[1];
    const float* b = (const float*)d_in[2];

    float* g_out = (float*)d_out;                       // [NTOK, 8]
    float* i_out = g_out + (size_t)NTOK * TOPK;         // [NTOK, 8] indices as float
    float* s_out = i_out + (size_t)NTOK * TOPK;         // [NTOK, 64]

    const size_t OFF_LIST = 1024;
    const size_t OFF_BLOB = 131072;
    const size_t WS_NEED  = OFF_BLOB + (size_t)NSTEP * 16384;   // +1 MB blob
    if (ws_size < WS_NEED) return;

    char* ws = (char*)d_ws;
    int* cnt  = (int*)ws;
    int* list = (int*)(ws + OFF_LIST);
    unsigned char* blob = (unsigned char*)(ws + OFF_BLOB);
    int cap = NTOK;

    prep_w<<<NSTEP, 256, 0, stream>>>(W, blob, cnt);
    bulk_kernel<<<NTOK / TPB, 512, 0, stream>>>(x, blob, b,
                                                g_out, i_out, s_out,
                                                cnt, list, cap);
    refine64<<<256, 256, 0, stream>>>(x, W, b, g_out, i_out, s_out,
                                      cnt, list, cap);
}

// Round 16
// 158.726 us; speedup vs baseline: 1.3763x; 1.3283x over previous
//
#include <hip/hip_runtime.h>
#include <cmath>

// Problem constants (B=4, S=4096, D=4096, E=64, K=8)
#define NTOK 16384
#define DDIM 4096
#define NEXP 64
#define TOPK 8
#define TPB   256               // tokens per block (bulk)
#define NKS   8                 // K-split ways across blocks
#define KSL   (DDIM / NKS)      // 512 k per slice
#define BK    32                // K per staged step
#define NSTEP (KSL / BK)        // 16
#define EPS_GAP 6e-5f           // ambiguity margin; trunc-split sigma ~3e-6 (20x)

typedef __attribute__((ext_vector_type(8))) short short8;   // 8 bf16
typedef __attribute__((ext_vector_type(4))) float f32x4;

__device__ __forceinline__ void gload16(const void* g, void* l) {
    __builtin_amdgcn_global_load_lds(
        (const __attribute__((address_space(1))) unsigned int*)g,
        (__attribute__((address_space(3))) unsigned int*)l, 16, 0, 0);
}

// trunc split: hi = top 16 bits (residual exact), lo = trunc16(f - hi).
#define CVT1(f, hOut, lOut, j) do {                                          \
    unsigned _u = __builtin_bit_cast(unsigned, (float)(f));                  \
    float _hf = __builtin_bit_cast(float, _u & 0xFFFF0000u);                 \
    hOut[j] = (short)(_u >> 16);                                             \
    lOut[j] = (short)(__builtin_bit_cast(unsigned, (float)((f) - _hf)) >> 16);\
} while (0)
#define CONV8(vA, vB, hOut, lOut) do {                       \
    CVT1(vA.x, hOut, lOut, 0); CVT1(vA.y, hOut, lOut, 1);    \
    CVT1(vA.z, hOut, lOut, 2); CVT1(vA.w, hOut, lOut, 3);    \
    CVT1(vB.x, hOut, lOut, 4); CVT1(vB.y, hOut, lOut, 5);    \
    CVT1(vB.z, hOut, lOut, 6); CVT1(vB.w, hOut, lOut, 7);    \
} while (0)

// ---------------------------------------------------------------------------
// Kernel 0 (R10/R14-verified): W -> lane-ordered bf16 hi/lo blob.
// blob[c32 0..127][n 0..3][granule=lane 0..63][16B], lo at +1024 within n.
// Consumer lane l: expert e = n*16+(l&15), k = c*32+(l>>4)*8+j.
// ---------------------------------------------------------------------------
__global__ __launch_bounds__(256) void prep_w(const float* __restrict__ W,
                                              unsigned char* __restrict__ blob,
                                              int* __restrict__ cnts)
{
    __shared__ float tile[32][65];
    const int c = blockIdx.x;
    const int t = threadIdx.x;
    if (c == 0 && t < 4) cnts[t] = 0;
    {
        const int r = t >> 3, q = t & 7;
        float4 v0 = *reinterpret_cast<const float4*>(
            &W[(size_t)(c * 32 + r) * NEXP + q * 8]);
        float4 v1 = *reinterpret_cast<const float4*>(
            &W[(size_t)(c * 32 + r) * NEXP + q * 8 + 4]);
        tile[r][q * 8 + 0] = v0.x; tile[r][q * 8 + 1] = v0.y;
        tile[r][q * 8 + 2] = v0.z; tile[r][q * 8 + 3] = v0.w;
        tile[r][q * 8 + 4] = v1.x; tile[r][q * 8 + 5] = v1.y;
        tile[r][q * 8 + 6] = v1.z; tile[r][q * 8 + 7] = v1.w;
    }
    __syncthreads();
    {
        const int el   = t & 15;
        const int kgrp = (t >> 4) & 3;
        const int n    = t >> 6;
        short8 hv, lv;
#pragma unroll
        for (int j = 0; j < 8; ++j) {
            float f = tile[kgrp * 8 + j][n * 16 + el];
            CVT1(f, hv, lv, j);
        }
        unsigned char* base = blob + (size_t)c * 8192 + n * 2048 +
                              (kgrp * 16 + el) * 16;
        *reinterpret_cast<short8*>(base)        = hv;   // hi
        *reinterpret_cast<short8*>(base + 1024) = lv;   // lo
    }
}

// ---------------------------------------------------------------------------
// Kernel 1: traffic-minimal bulk GEMM. Grid 512 = 64 tokgrp x 8 K-slices
// (2 blocks/CU). Block = 256 tok x 64 exp x 512-k slice, BK=32 -> 16 steps.
// B total traffic 64 MB (vs 512 in R7); A read once; partials 16 MB to ws.
// LDS 80KB: A dbuf 2x32KB fp32 (granule XOR (row&7) swizzle, pre-swizzled
// global source), B dbuf 2x8KB (linear copy of lane-ordered blob chunk).
// 8 waves: wave w = tokens [w*32, w*32+32) x all 64 experts.
// ---------------------------------------------------------------------------
__global__ __launch_bounds__(512, 4) void bulk_kernel(
    const float* __restrict__ x, const unsigned char* __restrict__ blob,
    float* __restrict__ part)
{
    __shared__ __align__(16) unsigned char smem[81920];

    const int tid  = threadIdx.x;
    const int l    = tid & 63;
    const int w    = tid >> 6;
    const int tokg = blockIdx.x >> 3;
    const int ks   = blockIdx.x & 7;
    const int tok0 = tokg * TPB;

    // ---- stager: instr q covers tokens [q*64,q*64+64); per-lane pre-swizzle
#define DECLA(q) const float* aSrc##q = x +                                   \
    (size_t)(tok0 + q * 64 + (tid >> 3)) * DDIM + ks * KSL +                  \
    ((((tid & 7) ^ ((tid >> 3) & 7))) << 2);
    DECLA(0) DECLA(1) DECLA(2) DECLA(3)
#undef DECLA
    const unsigned char* bSrc = blob + (size_t)(ks * NSTEP) * 8192 + tid * 16;

#define STAGE(buf, c) do {                                                    \
    unsigned char* _a = smem + (buf) * 32768;                                 \
    gload16(aSrc0 + (size_t)(c) * BK, _a + 0 * 8192 + tid * 16);              \
    gload16(aSrc1 + (size_t)(c) * BK, _a + 1 * 8192 + tid * 16);              \
    gload16(aSrc2 + (size_t)(c) * BK, _a + 2 * 8192 + tid * 16);              \
    gload16(aSrc3 + (size_t)(c) * BK, _a + 3 * 8192 + tid * 16);              \
    gload16(bSrc + (size_t)(c) * 8192, smem + 65536 + (buf) * 8192 + tid * 16);\
} while (0)

    // ---- compute-lane constants ----
    const int mt   = l & 15;
    const int kgrp = l >> 4;
    const int sw   = mt & 7;
    const int row0 = w * 32 + mt;
    const int row1 = row0 + 16;
    const int aoff00 = row0 * 128 + (((kgrp * 2    ) ^ sw) << 4);
    const int aoff01 = row0 * 128 + (((kgrp * 2 + 1) ^ sw) << 4);
    const int aoff10 = row1 * 128 + (((kgrp * 2    ) ^ sw) << 4);
    const int aoff11 = row1 * 128 + (((kgrp * 2 + 1) ^ sw) << 4);

    f32x4 acc00 = (f32x4){0.f,0.f,0.f,0.f}, acc01 = acc00, acc02 = acc00, acc03 = acc00;
    f32x4 acc10 = acc00, acc11 = acc00, acc12 = acc00, acc13 = acc00;

#define MFMA3(accv, AH, AL, BH, BL) do {                                      \
    accv = __builtin_amdgcn_mfma_f32_16x16x32_bf16(AH, BH, accv, 0, 0, 0);    \
    accv = __builtin_amdgcn_mfma_f32_16x16x32_bf16(AH, BL, accv, 0, 0, 0);    \
    accv = __builtin_amdgcn_mfma_f32_16x16x32_bf16(AL, BH, accv, 0, 0, 0);    \
} while (0)

#define COMPUTE(buf) do {                                                     \
    const unsigned char* _a  = smem + (buf) * 32768;                          \
    const unsigned char* _bb = smem + 65536 + (buf) * 8192;                   \
    float4 A0 = *reinterpret_cast<const float4*>(_a + aoff00);                \
    float4 A1 = *reinterpret_cast<const float4*>(_a + aoff01);                \
    float4 A2 = *reinterpret_cast<const float4*>(_a + aoff10);                \
    float4 A3 = *reinterpret_cast<const float4*>(_a + aoff11);                \
    short8 ah0, al0, ah1, al1;                                                \
    CONV8(A0, A1, ah0, al0);                                                  \
    CONV8(A2, A3, ah1, al1);                                                  \
    {                                                                         \
        short8 bh = *reinterpret_cast<const short8*>(_bb + 0 * 2048 + l * 16);\
        short8 bl = *reinterpret_cast<const short8*>(_bb + 0 * 2048 + 1024 + l * 16);\
        MFMA3(acc00, ah0, al0, bh, bl); MFMA3(acc10, ah1, al1, bh, bl);       \
    }                                                                         \
    {                                                                         \
        short8 bh = *reinterpret_cast<const short8*>(_bb + 1 * 2048 + l * 16);\
        short8 bl = *reinterpret_cast<const short8*>(_bb + 1 * 2048 + 1024 + l * 16);\
        MFMA3(acc01, ah0, al0, bh, bl); MFMA3(acc11, ah1, al1, bh, bl);       \
    }                                                                         \
    {                                                                         \
        short8 bh = *reinterpret_cast<const short8*>(_bb + 2 * 2048 + l * 16);\
        short8 bl = *reinterpret_cast<const short8*>(_bb + 2 * 2048 + 1024 + l * 16);\
        MFMA3(acc02, ah0, al0, bh, bl); MFMA3(acc12, ah1, al1, bh, bl);       \
    }                                                                         \
    {                                                                         \
        short8 bh = *reinterpret_cast<const short8*>(_bb + 3 * 2048 + l * 16);\
        short8 bl = *reinterpret_cast<const short8*>(_bb + 3 * 2048 + 1024 + l * 16);\
        MFMA3(acc03, ah0, al0, bh, bl); MFMA3(acc13, ah1, al1, bh, bl);       \
    }                                                                         \
} while (0)

#define WAITBAR asm volatile("s_waitcnt vmcnt(0) lgkmcnt(0)\n\ts_barrier" ::: "memory")

    STAGE(0, 0);
    WAITBAR;
    for (int c = 0; c < NSTEP; ++c) {
        if (c + 1 < NSTEP) STAGE((c + 1) & 1, c + 1);
        COMPUTE(c & 1);
        WAITBAR;
    }

    // ---- write fp32 partials: part[ks][tok][exp] (verified C mapping) ----
#define WRPART(tf, n, accv) do {                                              \
    _Pragma("unroll")                                                         \
    for (int r = 0; r < 4; ++r)                                               \
        part[((size_t)ks * NTOK + tok0 + w * 32 + tf * 16 + kgrp * 4 + r)     \
             * NEXP + n * 16 + mt] = accv[r];                                 \
} while (0)
    WRPART(0, 0, acc00); WRPART(0, 1, acc01); WRPART(0, 2, acc02); WRPART(0, 3, acc03);
    WRPART(1, 0, acc10); WRPART(1, 1, acc11); WRPART(1, 2, acc12); WRPART(1, 3, acc13);
#undef WRPART
#undef STAGE
#undef COMPUTE
#undef MFMA3
#undef WAITBAR
}

// ---------------------------------------------------------------------------
// Kernel 2: combine slices (fixed order) + bias + sigmoid + top-10 + flag.
// 256 blocks x 256 thr; block = 64 tokens.
// ---------------------------------------------------------------------------
__global__ __launch_bounds__(256) void combine_kernel(
    const float* __restrict__ part, const float* __restrict__ b,
    float* __restrict__ g_out, float* __restrict__ i_out,
    float* __restrict__ s_out,
    int* __restrict__ flag_cnt, int* __restrict__ flag_list, int cap)
{
    __shared__ float ls[64 * 68];
    const int tid  = threadIdx.x;
    const int tok0 = blockIdx.x * 64;
    const int t    = tid >> 2;
    const int e16  = (tid & 3) * 16;

#pragma unroll
    for (int g = 0; g < 4; ++g) {
        const int e = e16 + g * 4;
        const size_t base = ((size_t)(tok0 + t)) * NEXP + e;
        float4 a = *reinterpret_cast<const float4*>(&part[base]);
#pragma unroll
        for (int s = 1; s < NKS; ++s) {
            float4 v = *reinterpret_cast<const float4*>(
                &part[(size_t)s * NTOK * NEXP + base]);
            a.x += v.x; a.y += v.y; a.z += v.z; a.w += v.w;
        }
        float4 bv = *reinterpret_cast<const float4*>(&b[e]);
        a.x += bv.x; a.y += bv.y; a.z += bv.z; a.w += bv.w;
        *reinterpret_cast<float4*>(&ls[t * 68 + e]) = a;
        float4 sv;
        sv.x = 1.0f / (1.0f + __expf(-a.x));
        sv.y = 1.0f / (1.0f + __expf(-a.y));
        sv.z = 1.0f / (1.0f + __expf(-a.z));
        sv.w = 1.0f / (1.0f + __expf(-a.w));
        *reinterpret_cast<float4*>(&s_out[(size_t)(tok0 + t) * NEXP + e]) = sv;
    }
    __syncthreads();

    if (tid < 64) {
        const int tk = tid;
        float val[10];
        int   idx[10];
#pragma unroll
        for (int j = 0; j < 10; ++j) { val[j] = -1e30f; idx[j] = 0; }
        for (int e = 0; e < NEXP; ++e) {
            float v = ls[tk * 68 + e];
            int  ei = e;
#pragma unroll
            for (int j = 0; j < 10; ++j) {
                if (v > val[j]) {   // strict > keeps lower index first on ties
                    float tv = val[j]; val[j] = v; v = tv;
                    int   ti = idx[j]; idx[j] = ei; ei = ti;
                }
            }
        }
        bool flag = false;
#pragma unroll
        for (int j = 0; j < 9; ++j) flag |= (val[j] - val[j + 1]) < EPS_GAP;

        float gg[TOPK], gsum = 0.0f;
#pragma unroll
        for (int j = 0; j < TOPK; ++j) {
            gg[j] = 1.0f / (1.0f + __expf(-val[j]));
            gsum += gg[j];
        }
        const float inv = 1.0f / gsum;
        const int tglob = tok0 + tk;
#pragma unroll
        for (int j = 0; j < TOPK; ++j) {
            g_out[(size_t)tglob * TOPK + j] = gg[j] * inv;
            i_out[(size_t)tglob * TOPK + j] = (float)idx[j];
        }
        if (flag) {
            int p = atomicAdd(flag_cnt, 1);
            if (p < cap) flag_list[p] = tglob;
        }
    }
}

// ---------------------------------------------------------------------------
// Kernel 3: f64-exact re-rank of ambiguous tokens (verified).
// ---------------------------------------------------------------------------
__global__ __launch_bounds__(256) void refine64(
    const float* __restrict__ x, const float* __restrict__ W,
    const float* __restrict__ b, float* __restrict__ g_out,
    float* __restrict__ i_out, float* __restrict__ s_out,
    const int* __restrict__ flag_cnt, const int* __restrict__ flag_list,
    int flag_cap)
{
    __shared__ float  xs2[DDIM];
    __shared__ double red[4][NEXP];
    __shared__ double sc[NEXP];

    const int tid = threadIdx.x;
    int count = *flag_cnt;
    if (count > flag_cap) count = flag_cap;

    for (int it = blockIdx.x; it < count; it += gridDim.x) {
        const int tok = flag_list[it];
        __syncthreads();
#pragma unroll
        for (int q = 0; q < 4; ++q) {
            int fi = tid + 256 * q;
            *reinterpret_cast<float4*>(&xs2[fi * 4]) =
                *reinterpret_cast<const float4*>(&x[(size_t)tok * DDIM + fi * 4]);
        }
        __syncthreads();

        const int e    = tid & 63;
        const int pt   = tid >> 6;
        const int dbase = pt * (DDIM / 4);
        double a = 0.0;
        for (int d = 0; d < DDIM / 4; ++d) {
            a = fma((double)xs2[dbase + d],
                    (double)W[(size_t)(dbase + d) * NEXP + e], a);
        }
        red[pt][e] = a;
        __syncthreads();

        if (tid < NEXP) {
            double z = ((red[0][tid] + red[1][tid]) +
                        (red[2][tid] + red[3][tid])) + (double)b[tid];
            double s = 1.0 / (1.0 + exp(-z));
            sc[tid] = s;
            s_out[(size_t)tok * NEXP + tid] = (float)s;
        }
        __syncthreads();

        if (tid == 0) {
            double val[TOPK];
            int    idx[TOPK];
#pragma unroll
            for (int j = 0; j < TOPK; ++j) { val[j] = -1e30; idx[j] = 0; }
            for (int e2 = 0; e2 < NEXP; ++e2) {
                double v = sc[e2];
                int   ei = e2;
#pragma unroll
                for (int j = 0; j < TOPK; ++j) {
                    if (v > val[j]) {
                        double tv = val[j]; val[j] = v; v = tv;
                        int    ti = idx[j]; idx[j] = ei; ei = ti;
                    }
                }
            }
            double gsum = 0.0;
#pragma unroll
            for (int j = 0; j < TOPK; ++j) gsum += val[j];
            const double inv = 1.0 / gsum;
#pragma unroll
            for (int j = 0; j < TOPK; ++j) {
                g_out[(size_t)tok * TOPK + j] = (float)(val[j] * inv);
                i_out[(size_t)tok * TOPK + j] = (float)idx[j];
            }
        }
        __syncthreads();
    }
}

// ---------------------------------------------------------------------------
extern "C" void kernel_launch(void* const* d_in, const int* in_sizes, int n_in,
                              void* d_out, int out_size, void* d_ws, size_t ws_size,
                              hipStream_t stream)
{
    (void)in_sizes; (void)n_in; (void)out_size;
    const float* x = (const float*)d_in[0];
    const float* W = (const float*)d_in[1];
    const float* b = (const float*)d_in[2];

    float* g_out = (float*)d_out;                       // [NTOK, 8]
    float* i_out = g_out + (size_t)NTOK * TOPK;         // [NTOK, 8] indices as float
    float* s_out = i_out + (size_t)NTOK * TOPK;         // [NTOK, 64]

    const size_t OFF_LIST = 1024;
    const size_t OFF_BLOB = 131072;
    const size_t OFF_PART = OFF_BLOB + 128u * 8192u;            // +1 MB
    const size_t WS_NEED  = OFF_PART + (size_t)NKS * NTOK * NEXP * 4;  // +32 MB
    if (ws_size < WS_NEED) return;

    char* ws = (char*)d_ws;
    int* cnt  = (int*)ws;
    int* list = (int*)(ws + OFF_LIST);
    unsigned char* blob = (unsigned char*)(ws + OFF_BLOB);
    float* part = (float*)(ws + OFF_PART);
    int cap = NTOK;

    prep_w<<<128, 256, 0, stream>>>(W, blob, cnt);
    bulk_kernel<<<(NTOK / TPB) * NKS, 512, 0, stream>>>(x, blob, part);
    combine_kernel<<<NTOK / 64, 256, 0, stream>>>(part, b, g_out, i_out, s_out,
                                                  cnt, list, cap);
    refine64<<<256, 256, 0, stream>>>(x, W, b, g_out, i_out, s_out,
                                      cnt, list, cap);
}